// Round 5
// baseline (1330.491 us; speedup 1.0000x reference)
//
#include <hip/hip_runtime.h>

#define N_TOKENS 32768
#define K_CODES  1024
#define DIM      256
#define BETA     0.25f

typedef unsigned long long u64;

// ---------------- init: wn[k] = ||w_k||^2, zero counts, keys = +inf ----------
__global__ void init_kernel(const float* __restrict__ w, float* __restrict__ wn,
                            int* __restrict__ counts, u64* __restrict__ keys) {
    int k = blockIdx.x;
    int lane = threadIdx.x;  // 64
    float4 v = *(const float4*)(w + (size_t)k * DIM + lane * 4);
    float s = v.x * v.x + v.y * v.y + v.z * v.z + v.w * v.w;
    #pragma unroll
    for (int off = 32; off; off >>= 1) s += __shfl_down(s, off);
    if (lane == 0) { wn[k] = s; counts[k] = 0; }
    if (lane < 32) keys[k * 32 + lane] = ~0ull;   // 1024*32 = 32768 keys
}

// ---------------- argmin: split-K fused distance-GEMM + atomicMin merge ----
// grid = 256 token-tiles x 4 code-quarters. Block: 128 tokens x 256 codes,
// 256 threads, micro-tile 8x16 (acc=128 regs; 96 B LDS per 128 FMA).
// LDS transposed [d][elem], ZLS=140 / WLS=276 with row-group shift
// 8*((c>>1)&1) and code-skew 4*((k>>6)&3).
// NOTE: skew must be injective over the 256-code tile: col(k)=k+4*((k>>6)&3)
// is strictly increasing (the round-4 bug was (k>>5)&3, which wraps at k=128
// and collides columns 128..139). Reads stay 2-way bank-aliased (free).
// Blocks merge per-token argmin via atomicMin on (sortable_dist<<32)|idx.
__global__ __launch_bounds__(256, 3) void argmin_kernel(
    const float* __restrict__ z, const float* __restrict__ w,
    const float* __restrict__ wn, u64* __restrict__ keys)
{
    constexpr int ZLS = 140, WLS = 276;
    __shared__ float zs[32 * ZLS];    // 17,920 B
    __shared__ float wsh[32 * WLS];   // 35,328 B

    const int tid = threadIdx.x;
    const int ty = tid >> 4;          // 0..15 -> 8-token group
    const int tx = tid & 15;          // 0..15 -> 16-code group
    const int tok0  = (blockIdx.x >> 2) * 128;
    const int kbase = (blockIdx.x & 3) * 256;

    const int zoffb = ty * 8;
    const int woffb = tx * 16 + 4 * ((tx >> 2) & 3);   // matches store skew

    float acc[8][16];
    #pragma unroll
    for (int i = 0; i < 8; i++)
        #pragma unroll
        for (int j = 0; j < 16; j++) acc[i][j] = 0.0f;

    for (int dt = 0; dt < 8; ++dt) {
        const int d0 = dt * 32;
        __syncthreads();   // previous chunk's LDS reads done
        {
            // stage z chunk: 128 tok x 32 d (4 float4/thread)
            float4 pz[4];
            #pragma unroll
            for (int i = 0; i < 4; i++) {
                int id = tid + i * 256; int t = id >> 3, c = id & 7;
                pz[i] = *(const float4*)(z + (size_t)(tok0 + t) * DIM + d0 + c * 4);
            }
            #pragma unroll
            for (int i = 0; i < 4; i++) {
                int id = tid + i * 256; int t = id >> 3, c = id & 7;
                int zc = t + 8 * ((c >> 1) & 1);
                zs[(c * 4 + 0) * ZLS + zc] = pz[i].x;
                zs[(c * 4 + 1) * ZLS + zc] = pz[i].y;
                zs[(c * 4 + 2) * ZLS + zc] = pz[i].z;
                zs[(c * 4 + 3) * ZLS + zc] = pz[i].w;
            }
            // stage w chunk: 256 codes x 32 d (8 float4/thread)
            float4 pw[8];
            #pragma unroll
            for (int i = 0; i < 8; i++) {
                int id = tid + i * 256; int k = id >> 3, c = id & 7;
                pw[i] = *(const float4*)(w + (size_t)(kbase + k) * DIM + d0 + c * 4);
            }
            #pragma unroll
            for (int i = 0; i < 8; i++) {
                int id = tid + i * 256; int k = id >> 3, c = id & 7;
                int wc = k + 4 * ((k >> 6) & 3) + 8 * ((c >> 1) & 1);  // injective
                wsh[(c * 4 + 0) * WLS + wc] = pw[i].x;
                wsh[(c * 4 + 1) * WLS + wc] = pw[i].y;
                wsh[(c * 4 + 2) * WLS + wc] = pw[i].z;
                wsh[(c * 4 + 3) * WLS + wc] = pw[i].w;
            }
        }
        __syncthreads();

        // compute: 32 layers x (8 tok x 16 codes)
        #pragma unroll 8
        for (int d = 0; d < 32; ++d) {
            int sh = 8 * ((d >> 3) & 1);
            float za[8], wa[16];
            *(float4*)&za[0] = *(const float4*)&zs[d * ZLS + sh + zoffb];
            *(float4*)&za[4] = *(const float4*)&zs[d * ZLS + sh + zoffb + 4];
            *(float4*)&wa[0]  = *(const float4*)&wsh[d * WLS + sh + woffb];
            *(float4*)&wa[4]  = *(const float4*)&wsh[d * WLS + sh + woffb + 4];
            *(float4*)&wa[8]  = *(const float4*)&wsh[d * WLS + sh + woffb + 8];
            *(float4*)&wa[12] = *(const float4*)&wsh[d * WLS + sh + woffb + 12];
            #pragma unroll
            for (int i = 0; i < 8; i++)
                #pragma unroll
                for (int j = 0; j < 16; j++)
                    acc[i][j] = fmaf(za[i], wa[j], acc[i][j]);
        }
    }

    // epilogue: dist = wn - 2*z.w (||z||^2 constant per row); per-thread min
    // over 16 codes, then shuffle-min across the 16-lane tx group, packed as
    // sortable (dist<<32)|idx so ties pick the smaller index (numpy argmin).
    float wnv[16];
    #pragma unroll
    for (int u = 0; u < 4; u++)
        *(float4*)&wnv[u * 4] = *(const float4*)(wn + kbase + tx * 16 + u * 4);

    u64 bkey[8];
    #pragma unroll
    for (int i = 0; i < 8; i++) {
        float bv = 3.4e38f; int bi = 0;
        #pragma unroll
        for (int j = 0; j < 16; j++) {
            float dist = wnv[j] - 2.0f * acc[i][j];
            if (dist < bv) { bv = dist; bi = kbase + tx * 16 + j; }
        }
        unsigned u = __float_as_uint(bv);
        unsigned s = (u & 0x80000000u) ? ~u : (u | 0x80000000u);
        bkey[i] = ((u64)s << 32) | (unsigned)bi;
    }
    #pragma unroll
    for (int m = 1; m < 16; m <<= 1) {
        #pragma unroll
        for (int i = 0; i < 8; i++) {
            u64 o = __shfl_xor(bkey[i], m);
            if (o < bkey[i]) bkey[i] = o;
        }
    }
    if (tx == 0) {
        #pragma unroll
        for (int i = 0; i < 8; i++)
            atomicMin(&keys[tok0 + ty * 8 + i], bkey[i]);
    }
}

// ---------------- gather + commitment loss + idx/counts ----------------
// wave (64 lanes) = one token (64 float4). 8192 waves x 4 iters.
__global__ void gather_loss_kernel(const float* __restrict__ z,
                                   const float* __restrict__ w,
                                   const u64* __restrict__ keys,
                                   float* __restrict__ zq_out,
                                   float* __restrict__ idxf,
                                   int* __restrict__ counts,
                                   float* __restrict__ partials)
{
    __shared__ float red[4];
    int tid = threadIdx.x;
    int lane = tid & 63;
    int wid = blockIdx.x * 4 + (tid >> 6);   // 0..8191
    float s = 0.0f;
    #pragma unroll
    for (int it = 0; it < 4; it++) {
        int tok = wid + it * 8192;
        u64 key = 0;
        if (lane == 0) key = keys[tok];
        key = __shfl(key, 0);
        int k = (int)(unsigned)(key & 0xFFFFFFFFull);
        float4 wv = *(const float4*)(w + (size_t)k * DIM + lane * 4);
        float4 zv = *(const float4*)(z + (size_t)tok * DIM + lane * 4);
        *(float4*)(zq_out + (size_t)tok * DIM + lane * 4) = wv;
        float dx = wv.x - zv.x, dy = wv.y - zv.y, dz = wv.z - zv.z, dw = wv.w - zv.w;
        s += dx * dx + dy * dy + dz * dz + dw * dw;
        if (lane == 0) {
            idxf[tok] = (float)k;
            atomicAdd(&counts[k], 1);
        }
    }
    #pragma unroll
    for (int off = 32; off; off >>= 1) s += __shfl_down(s, off);
    if (lane == 0) red[tid >> 6] = s;
    __syncthreads();
    if (tid == 0)
        partials[blockIdx.x] = red[0] + red[1] + red[2] + red[3];
}

// ---------------- perplexity + loss finalize ----------------
__global__ void finalize_kernel(const int* __restrict__ counts,
                                const float* __restrict__ partials,
                                float* __restrict__ loss_out,
                                float* __restrict__ ppl_out)
{
    __shared__ float redE[16], redL[16];
    int tid = threadIdx.x;  // 1024
    float e = (float)counts[tid] * (1.0f / (float)N_TOKENS);
    float t = -e * logf(e + 1e-10f);
    float p = partials[tid] + partials[tid + 1024];
    #pragma unroll
    for (int off = 32; off; off >>= 1) {
        t += __shfl_down(t, off);
        p += __shfl_down(p, off);
    }
    if ((tid & 63) == 0) { redE[tid >> 6] = t; redL[tid >> 6] = p; }
    __syncthreads();
    if (tid == 0) {
        float se = 0.0f, sl = 0.0f;
        #pragma unroll
        for (int i = 0; i < 16; i++) { se += redE[i]; sl += redL[i]; }
        *ppl_out = expf(se);
        *loss_out = BETA * sl / (float)((size_t)N_TOKENS * DIM);
    }
}

extern "C" void kernel_launch(void* const* d_in, const int* in_sizes, int n_in,
                              void* d_out, int out_size, void* d_ws, size_t ws_size,
                              hipStream_t stream) {
    const float* z = (const float*)d_in[0];
    const float* w = (const float*)d_in[1];
    float* out = (float*)d_out;

    // d_out layout (float): [0]=loss, [1..NT*D]=z_q_st, [..]=indices(float), [last]=perplexity
    float* loss_out = out;
    float* zq_out   = out + 1;
    float* idxf     = out + 1 + (size_t)N_TOKENS * DIM;
    float* ppl_out  = out + (out_size - 1);

    // ws layout (float idx): wn[0..1023] | counts[1024..2047] | partials[2048..4095]
    //                        | keys (u64) at byte 16384
    float* wn       = (float*)d_ws;
    int*   counts   = (int*)d_ws + 1024;
    float* partials = (float*)d_ws + 2048;
    u64*   keys     = (u64*)((char*)d_ws + 16384);

    init_kernel<<<K_CODES, 64, 0, stream>>>(w, wn, counts, keys);
    argmin_kernel<<<(N_TOKENS / 128) * 4, 256, 0, stream>>>(z, w, wn, keys);
    gather_loss_kernel<<<2048, 256, 0, stream>>>(z, w, keys, zq_out, idxf, counts, partials);
    finalize_kernel<<<1, 1024, 0, stream>>>(counts, partials, loss_out, ppl_out);
}

// Round 6
// 170.737 us; speedup vs baseline: 7.7926x; 7.7926x over previous
//
#include <hip/hip_runtime.h>

#define N_TOKENS 32768
#define K_CODES  1024
#define DIM      256
#define BETA     0.25f

typedef unsigned long long u64;
typedef _Float16 half8 __attribute__((ext_vector_type(8)));
typedef float floatx4 __attribute__((ext_vector_type(4)));

// ---------------- init: wn[k] = ||w_k||^2 (fp32 exact), counts=0, keys=+inf --
__global__ void init_kernel(const float* __restrict__ w, float* __restrict__ wn,
                            int* __restrict__ counts, u64* __restrict__ keys) {
    int k = blockIdx.x;
    int lane = threadIdx.x;  // 64
    float4 v = *(const float4*)(w + (size_t)k * DIM + lane * 4);
    float s = v.x * v.x + v.y * v.y + v.z * v.z + v.w * v.w;
    #pragma unroll
    for (int off = 32; off; off >>= 1) s += __shfl_down(s, off);
    if (lane == 0) { wn[k] = s; counts[k] = 0; }
    if (lane < 32) keys[k * 32 + lane] = ~0ull;   // 1024*32 = 32768 keys
}

// ---------------- argmin: fp16-split MFMA distance GEMM + atomicMin merge ----
// dot(z,w) = hi_z*hi_w + hi_z*lo_w + lo_z*hi_w  (fp16 split, lo*lo dropped:
// error ~2^-22 relative -> dist error ~1e-5, below fp32-reorder noise).
// grid = 8 code-blocks x 256 token-tiles (bx = q*256 + t -> same-tile blocks
// share XCD via %8). Block: 128 tok x 128 codes, 4 waves, wave tile 64x64
// (16 MFMA tiles x 3 products per K32 chunk). acc = 64 VGPR (round-5 lesson:
// keep register pressure low; launch_bounds(256,2) caps at 256, no spill).
// LDS rows = 40 halves (80 B): b128 frag reads AND staging writes map start
// bank-group (5r+q)%8 / (18t..) uniformly -> conflict-free throughput.
__global__ __launch_bounds__(256, 2) void argmin_kernel(
    const float* __restrict__ z, const float* __restrict__ w,
    const float* __restrict__ wn, u64* __restrict__ keys)
{
    constexpr int ZS = 40;   // halves per row (80 B, 16-B aligned)
    __shared__ _Float16 zhi[128 * ZS], zlo[128 * ZS];
    __shared__ _Float16 whi[128 * ZS], wlo[128 * ZS];
    __shared__ float wns[128];

    const int tid  = threadIdx.x;
    const int lane = tid & 63;
    const int wid  = tid >> 6;          // 0..3
    const int wm   = wid >> 1;          // token half
    const int wq   = wid & 1;           // code half
    const int t_   = blockIdx.x & 255;  // token tile
    const int q    = blockIdx.x >> 8;   // code block 0..7
    const int tok0  = t_ * 128;
    const int kbase = q * 128;

    if (tid < 128) wns[tid] = wn[kbase + tid];

    floatx4 acc[4][4];
    #pragma unroll
    for (int i = 0; i < 4; i++)
        #pragma unroll
        for (int j = 0; j < 4; j++)
            acc[i][j] = (floatx4){0.f, 0.f, 0.f, 0.f};

    const int r0 = tid >> 2;   // staging row (0..63), +64 for second item
    const int g0 = tid & 3;    // 8-dim group within 32-chunk

    for (int dt = 0; dt < 8; ++dt) {
        const int d0 = dt * 32;
        __syncthreads();   // previous chunk's fragment reads done

        // stage z chunk (128 tok x 32 d) and w chunk (128 codes x 32 d),
        // converting fp32 -> (hi,lo) fp16 pairs; one b128 write per array.
        #pragma unroll
        for (int s = 0; s < 2; s++) {
            int t = r0 + s * 64;
            const float* p = z + (size_t)(tok0 + t) * DIM + d0 + g0 * 8;
            float4 a = *(const float4*)p;
            float4 b = *(const float4*)(p + 4);
            float vals[8] = {a.x, a.y, a.z, a.w, b.x, b.y, b.z, b.w};
            half8 hv, lv;
            #pragma unroll
            for (int e = 0; e < 8; e++) {
                _Float16 h = (_Float16)vals[e];
                hv[e] = h;
                lv[e] = (_Float16)(vals[e] - (float)h);
            }
            *(half8*)&zhi[t * ZS + g0 * 8] = hv;
            *(half8*)&zlo[t * ZS + g0 * 8] = lv;
        }
        #pragma unroll
        for (int s = 0; s < 2; s++) {
            int t = r0 + s * 64;
            const float* p = w + (size_t)(kbase + t) * DIM + d0 + g0 * 8;
            float4 a = *(const float4*)p;
            float4 b = *(const float4*)(p + 4);
            float vals[8] = {a.x, a.y, a.z, a.w, b.x, b.y, b.z, b.w};
            half8 hv, lv;
            #pragma unroll
            for (int e = 0; e < 8; e++) {
                _Float16 h = (_Float16)vals[e];
                hv[e] = h;
                lv[e] = (_Float16)(vals[e] - (float)h);
            }
            *(half8*)&whi[t * ZS + g0 * 8] = hv;
            *(half8*)&wlo[t * ZS + g0 * 8] = lv;
        }
        __syncthreads();

        // fragments: A[m=lane&15][k=(lane>>4)*8+j], B[k][n=lane&15]
        half8 ah[4], al[4], bh[4], bl[4];
        const int koff = (lane >> 4) * 8;
        #pragma unroll
        for (int i = 0; i < 4; i++) {
            int za_off = (wm * 64 + i * 16 + (lane & 15)) * ZS + koff;
            ah[i] = *(const half8*)&zhi[za_off];
            al[i] = *(const half8*)&zlo[za_off];
            int wb_off = (wq * 64 + i * 16 + (lane & 15)) * ZS + koff;
            bh[i] = *(const half8*)&whi[wb_off];
            bl[i] = *(const half8*)&wlo[wb_off];
        }
        #pragma unroll
        for (int i = 0; i < 4; i++)
            #pragma unroll
            for (int j = 0; j < 4; j++) {
                acc[i][j] = __builtin_amdgcn_mfma_f32_16x16x32_f16(ah[i], bh[j], acc[i][j], 0, 0, 0);
                acc[i][j] = __builtin_amdgcn_mfma_f32_16x16x32_f16(ah[i], bl[j], acc[i][j], 0, 0, 0);
                acc[i][j] = __builtin_amdgcn_mfma_f32_16x16x32_f16(al[i], bh[j], acc[i][j], 0, 0, 0);
            }
    }

    // epilogue: dist = wn[code] - 2*dot (||z||^2 constant per row).
    // C layout: col(code) = lane&15, row(token) = (lane>>4)*4 + reg.
    #pragma unroll
    for (int i = 0; i < 4; i++) {
        #pragma unroll
        for (int r = 0; r < 4; r++) {
            float bv = 3.4e38f; int bi = 0;
            #pragma unroll
            for (int j = 0; j < 4; j++) {
                int cl = wq * 64 + j * 16 + (lane & 15);
                float dist = wns[cl] - 2.0f * acc[i][j][r];
                if (dist < bv) { bv = dist; bi = kbase + cl; }
            }
            unsigned uu = __float_as_uint(bv);
            unsigned ss = (uu & 0x80000000u) ? ~uu : (uu | 0x80000000u);
            u64 key = ((u64)ss << 32) | (unsigned)bi;
            #pragma unroll
            for (int m = 1; m < 16; m <<= 1) {
                u64 o = __shfl_xor(key, m);
                if (o < key) key = o;
            }
            if ((lane & 15) == 0) {
                int token = tok0 + wm * 64 + i * 16 + (lane >> 4) * 4 + r;
                atomicMin(&keys[token], key);
            }
        }
    }
}

// ---------------- gather + commitment loss + idx/counts ----------------
// wave (64 lanes) = one token (64 float4). 8192 waves x 4 iters.
__global__ void gather_loss_kernel(const float* __restrict__ z,
                                   const float* __restrict__ w,
                                   const u64* __restrict__ keys,
                                   float* __restrict__ zq_out,
                                   float* __restrict__ idxf,
                                   int* __restrict__ counts,
                                   float* __restrict__ partials)
{
    __shared__ float red[4];
    int tid = threadIdx.x;
    int lane = tid & 63;
    int wid = blockIdx.x * 4 + (tid >> 6);   // 0..8191
    float s = 0.0f;
    #pragma unroll
    for (int it = 0; it < 4; it++) {
        int tok = wid + it * 8192;
        u64 key = 0;
        if (lane == 0) key = keys[tok];
        key = __shfl(key, 0);
        int k = (int)(unsigned)(key & 0xFFFFFFFFull);
        float4 wv = *(const float4*)(w + (size_t)k * DIM + lane * 4);
        float4 zv = *(const float4*)(z + (size_t)tok * DIM + lane * 4);
        *(float4*)(zq_out + (size_t)tok * DIM + lane * 4) = wv;
        float dx = wv.x - zv.x, dy = wv.y - zv.y, dz = wv.z - zv.z, dw = wv.w - zv.w;
        s += dx * dx + dy * dy + dz * dz + dw * dw;
        if (lane == 0) {
            idxf[tok] = (float)k;
            atomicAdd(&counts[k], 1);
        }
    }
    #pragma unroll
    for (int off = 32; off; off >>= 1) s += __shfl_down(s, off);
    if (lane == 0) red[tid >> 6] = s;
    __syncthreads();
    if (tid == 0)
        partials[blockIdx.x] = red[0] + red[1] + red[2] + red[3];
}

// ---------------- perplexity + loss finalize ----------------
__global__ void finalize_kernel(const int* __restrict__ counts,
                                const float* __restrict__ partials,
                                float* __restrict__ loss_out,
                                float* __restrict__ ppl_out)
{
    __shared__ float redE[16], redL[16];
    int tid = threadIdx.x;  // 1024
    float e = (float)counts[tid] * (1.0f / (float)N_TOKENS);
    float t = -e * logf(e + 1e-10f);
    float p = partials[tid] + partials[tid + 1024];
    #pragma unroll
    for (int off = 32; off; off >>= 1) {
        t += __shfl_down(t, off);
        p += __shfl_down(p, off);
    }
    if ((tid & 63) == 0) { redE[tid >> 6] = t; redL[tid >> 6] = p; }
    __syncthreads();
    if (tid == 0) {
        float se = 0.0f, sl = 0.0f;
        #pragma unroll
        for (int i = 0; i < 16; i++) { se += redE[i]; sl += redL[i]; }
        *ppl_out = expf(se);
        *loss_out = BETA * sl / (float)((size_t)N_TOKENS * DIM);
    }
}

extern "C" void kernel_launch(void* const* d_in, const int* in_sizes, int n_in,
                              void* d_out, int out_size, void* d_ws, size_t ws_size,
                              hipStream_t stream) {
    const float* z = (const float*)d_in[0];
    const float* w = (const float*)d_in[1];
    float* out = (float*)d_out;

    // d_out layout (float): [0]=loss, [1..NT*D]=z_q_st, [..]=indices(float), [last]=perplexity
    float* loss_out = out;
    float* zq_out   = out + 1;
    float* idxf     = out + 1 + (size_t)N_TOKENS * DIM;
    float* ppl_out  = out + (out_size - 1);

    // ws layout (float idx): wn[0..1023] | counts[1024..2047] | partials[2048..4095]
    //                        | keys (u64) at byte 16384
    float* wn       = (float*)d_ws;
    int*   counts   = (int*)d_ws + 1024;
    float* partials = (float*)d_ws + 2048;
    u64*   keys     = (u64*)((char*)d_ws + 16384);

    init_kernel<<<K_CODES, 64, 0, stream>>>(w, wn, counts, keys);
    argmin_kernel<<<8 * 256, 256, 0, stream>>>(z, w, wn, keys);
    gather_loss_kernel<<<2048, 256, 0, stream>>>(z, w, keys, zq_out, idxf, counts, partials);
    finalize_kernel<<<1, 1024, 0, stream>>>(counts, partials, loss_out, ppl_out);
}

// Round 7
// 159.138 us; speedup vs baseline: 8.3606x; 1.0729x over previous
//
#include <hip/hip_runtime.h>

#define N_TOKENS 32768
#define K_CODES  1024
#define DIM      256
#define BETA     0.25f

typedef unsigned long long u64;
typedef _Float16 half8 __attribute__((ext_vector_type(8)));
typedef float floatx4 __attribute__((ext_vector_type(4)));

// ---- init: wn[k]=||w_k||^2 (fp32 exact), counts=0, keys=+inf, w->hi/lo fp16 --
__global__ void init_kernel(const float* __restrict__ w, float* __restrict__ wn,
                            int* __restrict__ counts, u64* __restrict__ keys,
                            _Float16* __restrict__ whiG, _Float16* __restrict__ wloG) {
    int k = blockIdx.x;
    int lane = threadIdx.x;  // 64
    float4 v = *(const float4*)(w + (size_t)k * DIM + lane * 4);
    float vals[4] = {v.x, v.y, v.z, v.w};
    float s = 0.f;
    #pragma unroll
    for (int e = 0; e < 4; e++) {
        s += vals[e] * vals[e];
        _Float16 h = (_Float16)vals[e];
        whiG[k * DIM + lane * 4 + e] = h;
        wloG[k * DIM + lane * 4 + e] = (_Float16)(vals[e] - (float)h);
    }
    #pragma unroll
    for (int off = 32; off; off >>= 1) s += __shfl_down(s, off);
    if (lane == 0) { wn[k] = s; counts[k] = 0; }
    if (lane < 32) keys[k * 32 + lane] = ~0ull;   // 1024*32 = 32768 keys
}

// ---------------- argmin: fp16-split MFMA distance GEMM + atomicMin merge ----
// dot(z,w) = hi_z*hi_w + hi_z*lo_w + lo_z*hi_w  (lo*lo dropped, err ~1e-5).
// grid = 4 code-quarters x 256 token-tiles. Block: 128 tok x 256 codes,
// 4 waves, wave tile 64x128 (32 MFMA tiles x 3 products per K32 chunk;
// 24 b128 frag reads per 96 MFMA = 250 B/MFMA, down from 341 at 64x64).
// w tiles load pre-split fp16 from global (L2-resident, no conversion VALU);
// z converted in-kernel (4x redundancy only). acc=128 VGPR, bounds(256,2)
// caps at 256 - no spill (round-5 lesson: verify via WRITE_SIZE ~ MB-scale).
// LDS rows = 40 halves (80 B): b128 reads/writes hit the structural minimum
// 8 words/bank (the 2^23 conflict count in r6 = this minimum, not a problem).
__global__ __launch_bounds__(256, 2) void argmin_kernel(
    const float* __restrict__ z, const _Float16* __restrict__ whiG,
    const _Float16* __restrict__ wloG, const float* __restrict__ wn,
    u64* __restrict__ keys)
{
    constexpr int ZS = 40;   // halves per row (80 B, 16-B aligned)
    __shared__ _Float16 zhi[128 * ZS], zlo[128 * ZS];
    __shared__ _Float16 whi[256 * ZS], wlo[256 * ZS];
    __shared__ float wns[256];

    const int tid  = threadIdx.x;
    const int lane = tid & 63;
    const int wid  = tid >> 6;          // 0..3
    const int wm   = wid >> 1;          // token half (64)
    const int wq   = wid & 1;           // code half (128)
    const int t_   = blockIdx.x & 255;  // token tile
    const int q    = blockIdx.x >> 8;   // code quarter 0..3
    const int tok0  = t_ * 128;
    const int kbase = q * 256;

    wns[tid] = wn[kbase + tid];

    floatx4 acc[4][8];
    #pragma unroll
    for (int i = 0; i < 4; i++)
        #pragma unroll
        for (int j = 0; j < 8; j++)
            acc[i][j] = (floatx4){0.f, 0.f, 0.f, 0.f};

    const int r0 = tid >> 2;   // staging row (0..63)
    const int g0 = tid & 3;    // 8-half group within 32-chunk

    for (int dt = 0; dt < 8; ++dt) {
        const int d0 = dt * 32;
        __syncthreads();   // previous chunk's fragment reads done

        // stage z chunk (128 tok x 32 d): fp32 -> (hi,lo) fp16
        #pragma unroll
        for (int s = 0; s < 2; s++) {
            int t = r0 + s * 64;
            const float* p = z + (size_t)(tok0 + t) * DIM + d0 + g0 * 8;
            float4 a = *(const float4*)p;
            float4 b = *(const float4*)(p + 4);
            float vals[8] = {a.x, a.y, a.z, a.w, b.x, b.y, b.z, b.w};
            half8 hv, lv;
            #pragma unroll
            for (int e = 0; e < 8; e++) {
                _Float16 h = (_Float16)vals[e];
                hv[e] = h;
                lv[e] = (_Float16)(vals[e] - (float)h);
            }
            *(half8*)&zhi[t * ZS + g0 * 8] = hv;
            *(half8*)&zlo[t * ZS + g0 * 8] = lv;
        }
        // stage w chunk (256 codes x 32 d): pre-split fp16, pure copy
        #pragma unroll
        for (int s = 0; s < 4; s++) {
            int t = r0 + s * 64;
            size_t goff = (size_t)(kbase + t) * DIM + d0 + g0 * 8;
            *(half8*)&whi[t * ZS + g0 * 8] = *(const half8*)&whiG[goff];
            *(half8*)&wlo[t * ZS + g0 * 8] = *(const half8*)&wloG[goff];
        }
        __syncthreads();

        // fragments: A[m=lane&15][k=(lane>>4)*8+e], B[k][n=lane&15]
        const int koff = (lane >> 4) * 8;
        half8 ah[4], al[4];
        #pragma unroll
        for (int i = 0; i < 4; i++) {
            int off = (wm * 64 + i * 16 + (lane & 15)) * ZS + koff;
            ah[i] = *(const half8*)&zhi[off];
            al[i] = *(const half8*)&zlo[off];
        }
        #pragma unroll
        for (int j = 0; j < 8; j++) {
            int off = (wq * 128 + j * 16 + (lane & 15)) * ZS + koff;
            half8 bh = *(const half8*)&whi[off];
            half8 bl = *(const half8*)&wlo[off];
            #pragma unroll
            for (int i = 0; i < 4; i++) {
                acc[i][j] = __builtin_amdgcn_mfma_f32_16x16x32_f16(ah[i], bh, acc[i][j], 0, 0, 0);
                acc[i][j] = __builtin_amdgcn_mfma_f32_16x16x32_f16(ah[i], bl, acc[i][j], 0, 0, 0);
                acc[i][j] = __builtin_amdgcn_mfma_f32_16x16x32_f16(al[i], bh, acc[i][j], 0, 0, 0);
            }
        }
    }

    // epilogue: dist = wn[code] - 2*dot (||z||^2 constant per row).
    // C layout: col(code) = lane&15, row(token) = (lane>>4)*4 + reg.
    #pragma unroll
    for (int i = 0; i < 4; i++) {
        #pragma unroll
        for (int r = 0; r < 4; r++) {
            float bv = 3.4e38f; int bi = 0;
            #pragma unroll
            for (int j = 0; j < 8; j++) {
                int cl = wq * 128 + j * 16 + (lane & 15);
                float dist = wns[cl] - 2.0f * acc[i][j][r];
                if (dist < bv) { bv = dist; bi = kbase + cl; }
            }
            unsigned uu = __float_as_uint(bv);
            unsigned ss = (uu & 0x80000000u) ? ~uu : (uu | 0x80000000u);
            u64 key = ((u64)ss << 32) | (unsigned)bi;
            #pragma unroll
            for (int m = 1; m < 16; m <<= 1) {
                u64 o = __shfl_xor(key, m);
                if (o < key) key = o;
            }
            if ((lane & 15) == 0) {
                int token = tok0 + wm * 64 + i * 16 + (lane >> 4) * 4 + r;
                atomicMin(&keys[token], key);
            }
        }
    }
}

// ---------------- gather + commitment loss + idx/counts ----------------
// wave (64 lanes) = one token (64 float4). 8192 waves x 4 iters.
__global__ void gather_loss_kernel(const float* __restrict__ z,
                                   const float* __restrict__ w,
                                   const u64* __restrict__ keys,
                                   float* __restrict__ zq_out,
                                   float* __restrict__ idxf,
                                   int* __restrict__ counts,
                                   float* __restrict__ partials)
{
    __shared__ float red[4];
    int tid = threadIdx.x;
    int lane = tid & 63;
    int wid = blockIdx.x * 4 + (tid >> 6);   // 0..8191
    float s = 0.0f;
    #pragma unroll
    for (int it = 0; it < 4; it++) {
        int tok = wid + it * 8192;
        u64 key = 0;
        if (lane == 0) key = keys[tok];
        key = __shfl(key, 0);
        int k = (int)(unsigned)(key & 0xFFFFFFFFull);
        float4 wv = *(const float4*)(w + (size_t)k * DIM + lane * 4);
        float4 zv = *(const float4*)(z + (size_t)tok * DIM + lane * 4);
        *(float4*)(zq_out + (size_t)tok * DIM + lane * 4) = wv;
        float dx = wv.x - zv.x, dy = wv.y - zv.y, dz = wv.z - zv.z, dw = wv.w - zv.w;
        s += dx * dx + dy * dy + dz * dz + dw * dw;
        if (lane == 0) {
            idxf[tok] = (float)k;
            atomicAdd(&counts[k], 1);
        }
    }
    #pragma unroll
    for (int off = 32; off; off >>= 1) s += __shfl_down(s, off);
    if (lane == 0) red[tid >> 6] = s;
    __syncthreads();
    if (tid == 0)
        partials[blockIdx.x] = red[0] + red[1] + red[2] + red[3];
}

// ---------------- perplexity + loss finalize ----------------
__global__ void finalize_kernel(const int* __restrict__ counts,
                                const float* __restrict__ partials,
                                float* __restrict__ loss_out,
                                float* __restrict__ ppl_out)
{
    __shared__ float redE[16], redL[16];
    int tid = threadIdx.x;  // 1024
    float e = (float)counts[tid] * (1.0f / (float)N_TOKENS);
    float t = -e * logf(e + 1e-10f);
    float p = partials[tid] + partials[tid + 1024];
    #pragma unroll
    for (int off = 32; off; off >>= 1) {
        t += __shfl_down(t, off);
        p += __shfl_down(p, off);
    }
    if ((tid & 63) == 0) { redE[tid >> 6] = t; redL[tid >> 6] = p; }
    __syncthreads();
    if (tid == 0) {
        float se = 0.0f, sl = 0.0f;
        #pragma unroll
        for (int i = 0; i < 16; i++) { se += redE[i]; sl += redL[i]; }
        *ppl_out = expf(se);
        *loss_out = BETA * sl / (float)((size_t)N_TOKENS * DIM);
    }
}

extern "C" void kernel_launch(void* const* d_in, const int* in_sizes, int n_in,
                              void* d_out, int out_size, void* d_ws, size_t ws_size,
                              hipStream_t stream) {
    const float* z = (const float*)d_in[0];
    const float* w = (const float*)d_in[1];
    float* out = (float*)d_out;

    // d_out layout (float): [0]=loss, [1..NT*D]=z_q_st, [..]=indices(float), [last]=perplexity
    float* loss_out = out;
    float* zq_out   = out + 1;
    float* idxf     = out + 1 + (size_t)N_TOKENS * DIM;
    float* ppl_out  = out + (out_size - 1);

    // ws layout: wn f32[1024] | counts i32[1024] | partials f32[2048]
    //            | keys u64[32768] @ byte 16384 | whiG/wloG fp16[1024*256] @ 278528
    float* wn       = (float*)d_ws;
    int*   counts   = (int*)d_ws + 1024;
    float* partials = (float*)d_ws + 2048;
    u64*   keys     = (u64*)((char*)d_ws + 16384);
    _Float16* whiG  = (_Float16*)((char*)d_ws + 16384 + (size_t)N_TOKENS * 8);
    _Float16* wloG  = whiG + (size_t)K_CODES * DIM;

    init_kernel<<<K_CODES, 64, 0, stream>>>(w, wn, counts, keys, whiG, wloG);
    argmin_kernel<<<4 * 256, 256, 0, stream>>>(z, whiG, wloG, wn, keys);
    gather_loss_kernel<<<2048, 256, 0, stream>>>(z, w, keys, zq_out, idxf, counts, partials);
    finalize_kernel<<<1, 1024, 0, stream>>>(counts, partials, loss_out, ppl_out);
}